// Round 9
// baseline (287.695 us; speedup 1.0000x reference)
//
#include <hip/hip_runtime.h>

// CRF forward loss, MI355X — parallel-in-time segment matrix products.
// Exp domain: u_t = u_{t-1} · (E_t D_t),  E=exp(scores[t]), D=target mask.
// K1: 4096 waves = (128 b × 2 chains × 16 segs); each computes the 48×48
//     product Q_seg = (M_a ... M_{a+15})^T via CLASSIC v_mfma_f32_16x16x16_f16
//     (K=16: no padding, canonical documented A/B layout), fp32 acc, exact
//     power-of-2 renorm per matmul (exponent tracked in int).
//     C/D layout == B-frag layout for K=16: B_kb[Cc] = f16(acc[kb][Cc]*sc),
//     elementwise — zero cross-lane movement between matmuls.
// K2: 256 waves, sequential 16-segment matvec per (b,chain).
// K3: reduce 256 partials.
// Fallback (ws too small): round-5 barrier-per-step kernel (passing, 130 us).

constexpr int SEQ = 256;
constexpr int NTAG = 48;
constexpr int START_TAG = 46;
constexpr int END_TAG = 47;
constexpr float L2E = 1.4426950408889634f; // log2(e)
constexpr float LN2 = 0.6931471805599453f;
constexpr int NSEG = 16;
constexpr int SEGL = 16;

constexpr size_t QFLOATS = (size_t)128 * 2 * NSEG * 2304;
constexpr size_t QBYTES  = QFLOATS * 4;                    // 37,748,736
constexpr size_t EXBYTES = (size_t)128 * 2 * NSEG * 4;     // 16,384
constexpr size_t RBYTES  = 256 * 4;
constexpr size_t WS_NEED = QBYTES + EXBYTES + RBYTES;

typedef float    f32x4 __attribute__((ext_vector_type(4)));
typedef _Float16 f16x4 __attribute__((ext_vector_type(4)));

__device__ __forceinline__ float fexp2(float x){ return __builtin_amdgcn_exp2f(x); }
__device__ __forceinline__ float flog2(float x){ return __builtin_amdgcn_logf(x); }
__device__ __forceinline__ float rlane(float v, int l){
    return __uint_as_float(__builtin_amdgcn_readlane(__float_as_uint(v), l));
}

// ============================ K1: segment products ============================
__global__ __launch_bounds__(256, 2)
void crf_seg_kernel(const float* __restrict__ S, const void* __restrict__ tgtv,
                    const void* __restrict__ mskv, float* __restrict__ wsQ,
                    int* __restrict__ wsE)
{
    // wave -> (b, seg, chain); chain fastest so twin chains share the block/L2
    const int g     = blockIdx.x * 4 + (threadIdx.x >> 6);
    const int b     = g >> 5;
    const int seg   = (g >> 1) & 15;
    const int chain = g & 1;
    const int l = threadIdx.x & 63, m = l & 15, q = l >> 4;

    const bool pack8 = (((const int*)mskv)[0] != 1);
    const unsigned char* msk8  = (const unsigned char*)mskv;
    const int*           msk32 = (const int*)mskv;
    const unsigned char* tgt8  = (const unsigned char*)tgtv;
    const int*           tgt32 = (const int*)tgtv;

    int len = 0;
    #pragma unroll
    for (int r = 0; r < 4; ++r) {
        int idx = b * SEQ + r * 64 + l;
        int mm = pack8 ? (msk8[idx] != 0) : (msk32[idx] != 0);
        len += (int)__popcll(__ballot(mm));
    }

    const int a = 1 + seg * SEGL;
    const int tend = min(a + SEGL, len);

    f32x4 acc[3][3];
    #pragma unroll
    for (int R = 0; R < 3; ++R)
        #pragma unroll
        for (int Cc = 0; Cc < 3; ++Cc)
            #pragma unroll
            for (int r = 0; r < 4; ++r)
                acc[R][Cc][r] = (R == Cc && (q * 4 + r) == m) ? 1.0f : 0.0f;

    float sc = 1.0f;   // pending power-of-2 scale (exact)
    int   E  = 0;      // Q_true = acc * sc * 2^E

    for (int t = a; t < tend; ++t) {
        const float* Sb = S + ((size_t)(b * SEQ + t)) * 2304;
        bool tm[3] = {false, false, false};
        if (chain) {
            int tb = (b * SEQ + t) * NTAG + m;
            if (pack8) { tm[0] = tgt8[tb] != 0;  tm[1] = tgt8[tb + 16] != 0;  tm[2] = tgt8[tb + 32] != 0; }
            else       { tm[0] = tgt32[tb] != 0; tm[1] = tgt32[tb + 16] != 0; tm[2] = tgt32[tb + 32] != 0; }
        }
        // B fragments from current acc (old Q), elementwise f16 — no repacking:
        // B_kb[k=16kb+4q+e][n=16Cc+m] = acc[kb][Cc][e] * sc
        f16x4 bfr[3][3];
        #pragma unroll
        for (int kb = 0; kb < 3; ++kb)
            #pragma unroll
            for (int Cc = 0; Cc < 3; ++Cc)
                #pragma unroll
                for (int e = 0; e < 4; ++e)
                    bfr[kb][Cc][e] = (_Float16)(acc[kb][Cc][e] * sc);
        // A = M_t^T: A[j=16M0+m][k=16kb+4q+e] = exp(scores[t][k][j]), row j
        // zeroed if target-masked (chain 1).
        f16x4 afr[3][3];   // [M0][kb]
        #pragma unroll
        for (int M0 = 0; M0 < 3; ++M0) {
            const bool kill = chain && tm[M0];
            #pragma unroll
            for (int kb = 0; kb < 3; ++kb)
                #pragma unroll
                for (int e = 0; e < 4; ++e) {
                    float v = Sb[(kb * 16 + q * 4 + e) * 48 + M0 * 16 + m];
                    afr[M0][kb][e] = kill ? (_Float16)0.0f
                                          : (_Float16)fexp2(v * L2E);
                }
        }
        float mx = 0.0f;
        #pragma unroll
        for (int M0 = 0; M0 < 3; ++M0)
            #pragma unroll
            for (int Cc = 0; Cc < 3; ++Cc) {
                f32x4 d = {0.0f, 0.0f, 0.0f, 0.0f};
                d = __builtin_amdgcn_mfma_f32_16x16x16f16(afr[M0][0], bfr[0][Cc], d, 0, 0, 0);
                d = __builtin_amdgcn_mfma_f32_16x16x16f16(afr[M0][1], bfr[1][Cc], d, 0, 0, 0);
                d = __builtin_amdgcn_mfma_f32_16x16x16f16(afr[M0][2], bfr[2][Cc], d, 0, 0, 0);
                acc[M0][Cc] = d;
                mx = fmaxf(mx, fmaxf(fmaxf(d[0], d[1]), fmaxf(d[2], d[3])));
            }
        #pragma unroll
        for (int off = 1; off < 64; off <<= 1) mx = fmaxf(mx, __shfl_xor(mx, off));
        int ex = (int)((__float_as_uint(mx) >> 23) & 0xFF) - 126;  // -> [0.5,1)
        sc = __uint_as_float((unsigned)(127 - ex) << 23);          // exact 2^-ex
        E += ex;
    }

    float* Qo = wsQ + ((size_t)((b * 2 + chain) * NSEG + seg)) * 2304;
    #pragma unroll
    for (int R = 0; R < 3; ++R)
        #pragma unroll
        for (int Cc = 0; Cc < 3; ++Cc)
            #pragma unroll
            for (int r = 0; r < 4; ++r)
                Qo[(16 * R + q * 4 + r) * 48 + 16 * Cc + m] = acc[R][Cc][r] * sc;
    if (l == 0) wsE[(b * 2 + chain) * NSEG + seg] = E;
}

// ============================ K2: sequential combine ==========================
__global__ __launch_bounds__(64)
void crf_comb_kernel(const float* __restrict__ S, const void* __restrict__ tgtv,
                     const void* __restrict__ mskv, const float* __restrict__ wsQ,
                     const int* __restrict__ wsE, float* __restrict__ wsR)
{
    const int bid = blockIdx.x;
    const int b = bid >> 1, chain = bid & 1;
    const int l = threadIdx.x;
    const bool jok = (l < NTAG);
    const int j = jok ? l : 0;

    const bool pack8 = (((const int*)mskv)[0] != 1);
    const unsigned char* tgt8  = (const unsigned char*)tgtv;
    const int*           tgt32 = (const int*)tgtv;

    // u0 = exp2(scores[b,0,START,:]*L2E - M0); chain1 masked by tgt[b,0,:]
    float st0 = S[(size_t)b * SEQ * 2304 + START_TAG * 48 + j] * L2E;
    if (!jok) st0 = -1e30f;
    float M0 = st0;
    #pragma unroll
    for (int off = 1; off < 64; off <<= 1) M0 = fmaxf(M0, __shfl_xor(M0, off));
    float u = jok ? fexp2(st0 - M0) : 0.0f;
    if (chain && jok) {
        int ti = b * SEQ * NTAG + j;
        int tv0 = pack8 ? (int)tgt8[ti] : tgt32[ti];
        if (tv0) u = 0.0f;
    }
    float eu = M0;

    const int eb = (b * 2 + chain) * NSEG;
    const float* Qb = wsQ + (size_t)eb * 2304 + (size_t)(jok ? l : 47) * 48;

    float4 qa[12], qb[12];
    #pragma unroll
    for (int i = 0; i < 12; ++i) qa[i] = *(const float4*)(Qb + i * 4);

    auto step = [&](float4 (&qx)[12], int s) {
        float a0 = 0.f, a1 = 0.f, a2 = 0.f, a3 = 0.f;
        #pragma unroll
        for (int i = 0; i < 12; ++i) {
            a0 = fmaf(qx[i].x, rlane(u, 4 * i + 0), a0);
            a1 = fmaf(qx[i].y, rlane(u, 4 * i + 1), a1);
            a2 = fmaf(qx[i].z, rlane(u, 4 * i + 2), a2);
            a3 = fmaf(qx[i].w, rlane(u, 4 * i + 3), a3);
        }
        float un = (a0 + a1) + (a2 + a3);
        if (!jok) un = 0.0f;
        float mx = un;
        #pragma unroll
        for (int off = 1; off < 64; off <<= 1) mx = fmaxf(mx, __shfl_xor(mx, off));
        int ex = (int)((__float_as_uint(mx) >> 23) & 0xFF) - 126;
        un *= __uint_as_float((unsigned)(127 - ex) << 23);
        eu += (float)(ex + wsE[eb + s]);
        u = un;
    };

    #pragma unroll
    for (int p = 0; p < 8; ++p) {
        #pragma unroll
        for (int i = 0; i < 12; ++i)
            qb[i] = *(const float4*)(Qb + (size_t)(2 * p + 1) * 2304 + i * 4);
        step(qa, 2 * p);
        if (p < 7) {
            #pragma unroll
            for (int i = 0; i < 12; ++i)
                qa[i] = *(const float4*)(Qb + (size_t)(2 * p + 2) * 2304 + i * 4);
        }
        step(qb, 2 * p + 1);
    }

    if (l == END_TAG) {
        float r = (flog2(u) + eu) * LN2;       // back to ln domain
        if (chain) r = (u == 0.0f) ? 0.0f : -r;
        wsR[bid] = r;
    }
}

// ============================ K3: reduce ======================================
__global__ void crf_reduce_kernel(const float* __restrict__ ws, float* __restrict__ out)
{
    int l = threadIdx.x;                      // 64 threads
    float v = (ws[l] + ws[l + 64]) + (ws[l + 128] + ws[l + 192]);
    #pragma unroll
    for (int off = 32; off > 0; off >>= 1) v += __shfl_down(v, off);
    if (l == 0) out[0] = v;
}

// =================== Fallback: round-5 kernel (passing, 130 us) ===============
constexpr int FB_C = 12;
constexpr int FB_SLAB = NTAG * NTAG * 4;
constexpr int FB_NBUF = 6;
constexpr int FB_BUFS = FB_NBUF * FB_SLAB;
constexpr int FB_PART_OFF = FB_BUFS + 192;
constexpr int FB_TGT_OFF  = FB_PART_OFF + 2048;
constexpr int FB_LDS_TOT  = FB_TGT_OFF + 12352;

__global__ __launch_bounds__(256, 1)
void fb_chain_kernel(const float* __restrict__ S, const void* __restrict__ tgtv,
                     const void* __restrict__ mskv, float* __restrict__ ws)
{
    __shared__ __align__(16) unsigned char lds[FB_LDS_TOT];
    const int bid  = blockIdx.x;
    const int b    = bid & 127;
    const int tagc = bid >> 7;
    const int tid  = threadIdx.x;
    const int k    = tid >> 6;
    const int j    = tid & 63;
    const bool jok = (j < NTAG);
    const int jj   = jok ? j : 0;
    const int i0   = k * FB_C;

    const bool pack8 = (((const int*)mskv)[0] != 1);
    const unsigned char* msk8  = (const unsigned char*)mskv;
    const int*           msk32 = (const int*)mskv;

    int len = 0;
    #pragma unroll
    for (int r = 0; r < 4; ++r) {
        int idx = b * SEQ + r * 64 + j;
        int mm = pack8 ? (msk8[idx] != 0) : (msk32[idx] != 0);
        len += (int)__popcll(__ballot(mm));
    }

    if (tagc) {
        if (pack8) {
            const int4* src = (const int4*)((const unsigned char*)tgtv + (size_t)b * 12288);
            int4* dst = (int4*)(lds + FB_TGT_OFF);
            #pragma unroll
            for (int r = 0; r < 3; ++r) dst[tid * 3 + r] = src[tid * 3 + r];
        } else {
            const int4* src = (const int4*)((const int*)tgtv + (size_t)b * 12288);
            unsigned* dst = (unsigned*)(lds + FB_TGT_OFF);
            #pragma unroll
            for (int r = 0; r < 12; ++r) {
                int4 v = src[tid * 12 + r];
                dst[tid * 12 + r] = (unsigned)((v.x & 1) | ((v.y & 1) << 8) |
                                               ((v.z & 1) << 16) | ((v.w & 1) << 24));
            }
        }
    }
    if (tid < 12) *(float4*)(lds + FB_BUFS + tid * 16) = make_float4(0.f, 0.f, 0.f, 0.f);
    if (tid < 4)  *(float4*)(lds + FB_TGT_OFF + 12288 + tid * 16) = make_float4(0.f, 0.f, 0.f, 0.f);
    __syncthreads();

    const size_t sbf = (size_t)b * SEQ * NTAG * NTAG;
    const float  bias = jok ? 0.0f : -200.0f;

    float st0 = S[sbf + START_TAG * NTAG + jj] * L2E;
    if (!jok) st0 = -1e30f;
    float M0 = st0;
    #pragma unroll
    for (int off = 1; off < 64; off <<= 1) M0 = fmaxf(M0, __shfl_xor(M0, off));
    float u = jok ? fexp2(st0 - M0) : 0.0f;
    if (tagc && jok) {
        int tv0 = lds[FB_TGT_OFF + j];
        if (tv0) u = 0.0f;
    }
    float Mg = M0;

    const unsigned char* Sb = (const unsigned char*)S + sbf * 4;
    const int lo16 = k * 2304 + j * 16;
    const int lo4  = k * 2304 + 2048 + j * 4;

    auto stage = [&](int tau, int slot) {
        const unsigned char* gp = Sb + (size_t)tau * FB_SLAB;
        unsigned char* lp = lds + slot * FB_SLAB + k * 2304;
        __builtin_amdgcn_global_load_lds(
            (const __attribute__((address_space(1))) void*)(gp + lo16),
            (__attribute__((address_space(3))) void*)lp, 16, 0, 0);
        __builtin_amdgcn_global_load_lds(
            (const __attribute__((address_space(1))) void*)(gp + lo16 + 1024),
            (__attribute__((address_space(3))) void*)(lp + 1024), 16, 0, 0);
        __builtin_amdgcn_global_load_lds(
            (const __attribute__((address_space(1))) void*)(gp + lo4),
            (__attribute__((address_space(3))) void*)(lp + 2048), 4, 0, 0);
    };

    #pragma unroll
    for (int tau = 1; tau <= 5; ++tau) stage(tau, tau);
    asm volatile("s_waitcnt vmcnt(6)" ::: "memory");
    __builtin_amdgcn_sched_barrier(0);

    float EA[FB_C], EB[FB_C];
    {
        const float* ep = (const float*)(lds + 1 * FB_SLAB + i0 * 192);
        #pragma unroll
        for (int c = 0; c < FB_C; ++c) EA[c] = fexp2(fmaf(ep[c * 48 + j], L2E, bias));
    }

    float* part = (float*)(lds + FB_PART_OFF);
    const unsigned char* tl = lds + FB_TGT_OFF;
    int st_slot = 0;
    int rd_slot = 2;

    auto body = [&](float (&Ecur)[FB_C], float (&Enext)[FB_C], int t, int pb) {
        int tvv = 0;
        if (tagc) tvv = tl[t * 48 + j];
        float p0 = 0.f, p1 = 0.f;
        #pragma unroll
        for (int c = 0; c < FB_C; c += 2) {
            p0 = fmaf(Ecur[c],     rlane(u, i0 + c),     p0);
            p1 = fmaf(Ecur[c + 1], rlane(u, i0 + c + 1), p1);
        }
        part[pb * 256 + k * 64 + j] = p0 + p1;
        int tau = (t + 5 < len) ? (t + 5) : (len - 1);
        stage(tau, st_slot);
        if (++st_slot >= FB_NBUF) st_slot = 0;
        if (t + 1 < len) {
            const float* ep = (const float*)(lds + rd_slot * FB_SLAB + i0 * 192);
            #pragma unroll
            for (int c = 0; c < FB_C; ++c)
                Enext[c] = fexp2(fmaf(ep[c * 48 + j], L2E, bias));
        }
        if (++rd_slot >= FB_NBUF) rd_slot = 0;
        __builtin_amdgcn_sched_barrier(0);
        asm volatile("s_waitcnt lgkmcnt(0)" ::: "memory");
        asm volatile("s_waitcnt vmcnt(6)" ::: "memory");
        __builtin_amdgcn_sched_barrier(0);
        __builtin_amdgcn_s_barrier();
        __builtin_amdgcn_sched_barrier(0);
        float q0 = part[pb * 256 + j]       + part[pb * 256 + 64 + j];
        float q1 = part[pb * 256 + 128 + j] + part[pb * 256 + 192 + j];
        float un = q0 + q1;
        if (tagc && tvv) un = 0.0f;
        if (!jok) un = 0.0f;
        if ((t & 7) == 0) {
            float mx = un;
            #pragma unroll
            for (int off = 1; off < 64; off <<= 1) mx = fmaxf(mx, __shfl_xor(mx, off));
            int ex = (int)((__float_as_uint(mx) >> 23) & 0xFF) - 126;
            un = ldexpf(un, -ex);
            Mg += (float)ex;
        }
        u = un;
    };

    int t = 1;
    for (; t + 1 < len; t += 2) {
        body(EA, EB, t, 1);
        body(EB, EA, t + 1, 0);
    }
    if (t < len) body(EA, EB, t, 1);

    if (k == 0 && j == END_TAG) {
        float r = (Mg + flog2(u)) * LN2;
        if (tagc) r = (u == 0.0f) ? 0.0f : -r;
        ws[bid] = r;
    }
}

// ============================ launch ==========================================
extern "C" void kernel_launch(void* const* d_in, const int* in_sizes, int n_in,
                              void* d_out, int out_size, void* d_ws, size_t ws_size,
                              hipStream_t stream)
{
    const float* S   = (const float*)d_in[0];
    const void*  tgt = d_in[1];
    const void*  msk = d_in[2];
    float* out = (float*)d_out;

    if (ws_size >= WS_NEED) {
        float* wsQ = (float*)d_ws;
        int*   wsE = (int*)((char*)d_ws + QBYTES);
        float* wsR = (float*)((char*)d_ws + QBYTES + EXBYTES);
        crf_seg_kernel<<<1024, 256, 0, stream>>>(S, tgt, msk, wsQ, wsE);
        crf_comb_kernel<<<256, 64, 0, stream>>>(S, tgt, msk, wsQ, wsE, wsR);
        crf_reduce_kernel<<<1, 64, 0, stream>>>(wsR, out);
    } else {
        float* ws = (float*)d_ws;
        fb_chain_kernel<<<256, 256, 0, stream>>>(S, tgt, msk, ws);
        crf_reduce_kernel<<<1, 64, 0, stream>>>(ws, out);
    }
}